// Round 11
// baseline (318.924 us; speedup 1.0000x reference)
//
#include <hip/hip_runtime.h>

#define D 64
#define N_GRAPHS 128
#define D_OUT 16
#define BCAP 16384   // max edges per 256-node bucket (avg 6400, sigma ~80)
#define TILE 4096    // edges per bin block
#define ECAP 2048    // max edges per 32-node block staged in LDS (avg 800)
#define NREP 16      // pooled-accumulator replicas (contention dilution)

typedef unsigned short u16;
typedef unsigned int u32;
typedef unsigned char u8;
typedef __attribute__((ext_vector_type(8))) short bf16x8;
typedef __attribute__((ext_vector_type(4))) float f32x4;
typedef __attribute__((ext_vector_type(2))) float f32x2;

__device__ inline u16 f2bf(float f) {  // round-to-nearest-even
  u32 u = __float_as_uint(f);
  return (u16)((u + 0x7fffu + ((u >> 16) & 1u)) >> 16);
}
__device__ inline float bf2f(u16 b) { return __uint_as_float((u32)b << 16); }
__device__ inline f32x2 bfpair(u32 v) {
  return (f32x2){__uint_as_float(v << 16), __uint_as_float(v & 0xffff0000u)};
}

// ===========================================================================
// Merged front-end:
//   blocks [0, nbin)      : bin edges by dst>>8  -> binned  (for CSR)
//   blocks [nbin, 2*nbin) : bin edges by src>>8  -> binned2 (for pool3)
//   blocks [2*nbin, ...)  : x->bf16 convert + weight precompute
// cursors/cursors2 pre-zeroed by hipMemsetAsync.
// ===========================================================================
__global__ __launch_bounds__(256) void cvtbin_kernel(
    const float* __restrict__ xin, u16* __restrict__ hX, int n4, int nbin,
    const int* __restrict__ src, const int* __restrict__ dst,
    int* __restrict__ cursors, u32* __restrict__ binned,
    int* __restrict__ cursors2, u32* __restrict__ binned2,
    int n_edges, int nbuck,
    const float* __restrict__ Wrel1, const float* __restrict__ Wroot1,
    const float* __restrict__ Wrel2, const float* __restrict__ Wroot2,
    const float* __restrict__ Wrel3, const float* __restrict__ Wroot3,
    const float* __restrict__ Wlin, const float* __restrict__ brel3,
    const float* __restrict__ blin,
    float* __restrict__ M1, float* __restrict__ M2, float* __restrict__ cvec,
    u16* __restrict__ WbT1r, u16* __restrict__ WbT1o,
    u16* __restrict__ WbT2r, u16* __restrict__ WbT2o) {
  __shared__ u32 ent[TILE];
  __shared__ u8 ebk[TILE];
  __shared__ int hist[256];
  __shared__ int startb[256];
  __shared__ int cur[256];
  __shared__ int gbase[256];
  int t = threadIdx.x;

  if ((int)blockIdx.x < 2 * nbin) {
    // key = dst (first family) or src (second family); val = the other.
    bool bySrc = (int)blockIdx.x >= nbin;
    const int* keyArr = bySrc ? src : dst;
    const int* valArr = bySrc ? dst : src;
    int* curs = bySrc ? cursors2 : cursors;
    u32* bout = bySrc ? binned2 : binned;
    int lb = bySrc ? (int)blockIdx.x - nbin : (int)blockIdx.x;

    hist[t] = 0;
    __syncthreads();
    int base = lb * TILE;
    int cnt = n_edges - base;
    if (cnt > TILE) cnt = TILE;

    int mys[16], myd[16];
#pragma unroll
    for (int j = 0; j < 16; j++) {
      int i = base + t + j * 256;
      if (t + j * 256 < cnt) {
        mys[j] = valArr[i];
        myd[j] = keyArr[i];
        atomicAdd(&hist[myd[j] >> 8], 1);
      } else {
        myd[j] = -1;
      }
    }
    __syncthreads();
    int myc = hist[t];
    for (int off = 1; off < 256; off <<= 1) {
      int tmp = (t >= off) ? hist[t - off] : 0;
      __syncthreads();
      hist[t] += tmp;
      __syncthreads();
    }
    int excl = hist[t] - myc;
    startb[t] = excl;
    cur[t] = excl;
    __syncthreads();

#pragma unroll
    for (int j = 0; j < 16; j++) {
      if (myd[j] >= 0) {
        int b = myd[j] >> 8;
        int p = atomicAdd(&cur[b], 1);
        ent[p] = ((u32)myd[j] << 16) | (u32)mys[j];
        ebk[p] = (u8)b;
      }
    }
    __syncthreads();

    if (t < nbuck && myc > 0) gbase[t] = atomicAdd(&curs[t], myc);
    __syncthreads();

#pragma unroll
    for (int j = 0; j < 16; j++) {
      int p = t + j * 256;
      if (p < cnt) {
        int b = ebk[p];
        int gpos = gbase[b] + (p - startb[b]);
        if (gpos < BCAP) bout[(size_t)b * BCAP + gpos] = ent[p];
      }
    }
    return;
  }

  int cb = blockIdx.x - 2 * nbin;
  if (cb == 0) {
    if (t >= 240) {
      int o = t - 240;
      float c = blin[o];
#pragma unroll
      for (int j = 0; j < D; j++) c = fmaf(brel3[j], Wlin[j * D_OUT + o], c);
      cvec[o] = c;
    }
  } else if (cb <= 8) {
    int idx = (cb - 1) * 256 + t;
    const float* W = (idx < 1024) ? Wrel3 : Wroot3;
    float* M = (idx < 1024) ? M1 : M2;
    int id = idx & 1023;
    int k = id >> 4, o = id & 15;
    float acc = 0.0f;
#pragma unroll
    for (int j = 0; j < D; j++) acc = fmaf(W[k * D + j], Wlin[j * D_OUT + o], acc);
    M[id] = acc;
  } else if (cb <= 16) {
    int tid = (cb - 9) * 256 + t;
    int mat = tid >> 9;
    int r = tid & 511;
    int o = r >> 3;
    int k0 = (r & 7) * 8;
    const float* Wsrc = (mat == 0) ? Wrel1 : (mat == 1) ? Wroot1
                       : (mat == 2) ? Wrel2 : Wroot2;
    u16* Wdst = (mat == 0) ? WbT1r : (mat == 1) ? WbT1o
               : (mat == 2) ? WbT2r : WbT2o;
    u16 tmp[8];
#pragma unroll
    for (int j = 0; j < 8; j++) tmp[j] = f2bf(Wsrc[(k0 + j) * D + o]);
    uint4 pw;
    pw.x = (u32)tmp[0] | ((u32)tmp[1] << 16);
    pw.y = (u32)tmp[2] | ((u32)tmp[3] << 16);
    pw.z = (u32)tmp[4] | ((u32)tmp[5] << 16);
    pw.w = (u32)tmp[6] | ((u32)tmp[7] << 16);
    *(uint4*)&Wdst[o * D + k0] = pw;
  }
  int i = cb * 256 + t;
  if (i >= n4) return;
  float4 v = ((const float4*)xin)[i];
  ushort4 o4;
  o4.x = f2bf(v.x); o4.y = f2bf(v.y); o4.z = f2bf(v.z); o4.w = f2bf(v.w);
  ((ushort4*)hX)[i] = o4;
}

// ===========================================================================
// CSR pass 2 (unchanged from r10): per-node segments partitioned by src half.
// ===========================================================================
__global__ __launch_bounds__(256) void csr_kernel(
    const u32* __restrict__ binned, const int* __restrict__ cursors,
    u16* __restrict__ csr_src, int* __restrict__ offsets,
    int* __restrict__ midoff, int n_nodes, int nbuck, int halfThresh) {
  __shared__ int deg2[512];   // [node][half]
  __shared__ int cur2[512];
  __shared__ int red[256];
  __shared__ u16 lcsr[BCAP];
  int b = blockIdx.x, t = threadIdx.x;
  int cnt = cursors[b];
  if (cnt < 0) cnt = 0;
  if (cnt > BCAP) cnt = BCAP;

  int c = 0;
  if (t < b) {
    c = cursors[t];
    if (c < 0) c = 0;
    if (c > BCAP) c = BCAP;
  }
  red[t] = c;
  __syncthreads();
  for (int off = 128; off > 0; off >>= 1) {
    if (t < off) red[t] += red[t + off];
    __syncthreads();
  }
  int ebase = red[0];

  int nodeBase = b << 8;
  int nn = n_nodes - nodeBase;
  if (nn > 256) nn = 256;

  deg2[t] = 0;
  deg2[t + 256] = 0;
  __syncthreads();
  const u32* be = binned + (size_t)b * BCAP;
  for (int i = t; i < cnt; i += 256) {
    u32 e = be[i];
    int ln = (e >> 16) - nodeBase;
    int half = ((int)(e & 0xffffu) >= halfThresh) ? 1 : 0;
    atomicAdd(&deg2[ln * 2 + half], 1);
  }
  __syncthreads();
  int lowc = deg2[t * 2], highc = deg2[t * 2 + 1];
  int myTotal = lowc + highc;
  red[t] = myTotal;
  __syncthreads();
  for (int off = 1; off < 256; off <<= 1) {
    int tmp = (t >= off) ? red[t - off] : 0;
    __syncthreads();
    red[t] += tmp;
    __syncthreads();
  }
  int excl = red[t] - myTotal;
  cur2[t * 2] = excl;
  cur2[t * 2 + 1] = excl + lowc;
  if (t < nn) {
    offsets[nodeBase + t] = ebase + excl;
    midoff[nodeBase + t] = ebase + excl + lowc;
  }
  if (b == nbuck - 1 && t == 0) offsets[n_nodes] = ebase + cnt;
  __syncthreads();

  for (int i = t; i < cnt; i += 256) {
    u32 e = be[i];
    int ln = (e >> 16) - nodeBase;
    int half = ((int)(e & 0xffffu) >= halfThresh) ? 1 : 0;
    int p = atomicAdd(&cur2[ln * 2 + half], 1);
    lcsr[p] = (u16)(e & 0xffffu);
  }
  __syncthreads();
  for (int i = t; i < cnt; i += 256) csr_src[ebase + i] = lcsr[i];
}

#define ACC8(a, r) \
  a[0] += bfpair(r.x); a[1] += bfpair(r.y); a[2] += bfpair(r.z); a[3] += bfpair(r.w);

// Prologue: soff/smid -> LDS, degree-rank perm, contiguous csr run -> LDS.
#define GATHER_PROLOGUE(soff, smid, permAr, eidx, blockBase, n_nodes, offsets, midoff, csr_src, gsrc, ebase0, scnt) \
  {                                                                     \
    int t_ = threadIdx.x;                                               \
    if (t_ < 33) {                                                      \
      int idx = blockBase + t_;                                         \
      if (idx > n_nodes) idx = n_nodes;                                 \
      soff[t_] = offsets[idx];                                          \
    }                                                                   \
    if (t_ >= 64 && t_ < 96) {                                          \
      int n_ = t_ - 64;                                                 \
      int idx = blockBase + n_;                                         \
      smid[n_] = (idx < n_nodes) ? midoff[idx] : 0;                     \
    }                                                                   \
    __syncthreads();                                                    \
    ebase0 = soff[0];                                                   \
    int ecnt_ = soff[32] - ebase0;                                      \
    scnt = ecnt_ < ECAP ? ecnt_ : ECAP;                                 \
    gsrc = csr_src + ebase0;                                            \
    if (t_ < 32) {                                                      \
      int d_ = (blockBase + t_ < n_nodes) ? soff[t_ + 1] - soff[t_] : -1; \
      int r_ = 0;                                                       \
      for (int j_ = 0; j_ < 32; j_++) {                                 \
        int dj_ = (blockBase + j_ < n_nodes) ? soff[j_ + 1] - soff[j_] : -1; \
        if (dj_ > d_ || (dj_ == d_ && j_ < t_)) r_++;                   \
      }                                                                 \
      permAr[r_] = (u8)t_;                                              \
    }                                                                   \
    for (int e_ = t_; e_ < scnt; e_ += 256) eidx[e_] = gsrc[e_];        \
    __syncthreads();                                                    \
  }

#define IDX(i) ((i) < ECAP ? (int)eidx[i] : (int)gsrc[i])

// 4-deep unrolled gather body, full 16B row reads.
#define GATHER_LOOP(h, fo, ls, le, a0, a1)                                   \
  {                                                                          \
    int i = ls;                                                              \
    for (; i + 3 < le; i += 4) {                                             \
      int s0 = IDX(i), s1 = IDX(i + 1), s2 = IDX(i + 2), s3 = IDX(i + 3);    \
      uint4 r0 = *(const uint4*)(h + ((size_t)s0 << 6) + fo);                \
      uint4 r1 = *(const uint4*)(h + ((size_t)s1 << 6) + fo);                \
      uint4 r2 = *(const uint4*)(h + ((size_t)s2 << 6) + fo);                \
      uint4 r3 = *(const uint4*)(h + ((size_t)s3 << 6) + fo);                \
      ACC8(a0, r0) ACC8(a1, r1) ACC8(a0, r2) ACC8(a1, r3)                    \
    }                                                                        \
    for (; i < le; i++) {                                                    \
      int s0 = IDX(i);                                                       \
      uint4 r0 = *(const uint4*)(h + ((size_t)s0 << 6) + fo);                \
      ACC8(a0, r0)                                                           \
    }                                                                        \
  }

// ===========================================================================
// Fused layer (layers 1,2) — unchanged from r10.
// ===========================================================================
__global__ __launch_bounds__(256) void fused_layer_kernel(
    const u16* __restrict__ h, const int* __restrict__ offsets,
    const int* __restrict__ midoff, const u16* __restrict__ csr_src,
    const u16* __restrict__ WbTrel, const u16* __restrict__ WbTroot,
    const float* __restrict__ brel,
    u16* __restrict__ h_out, int n_nodes, int do_relu) {
  __shared__ __align__(16) u16 ldsA[32 * 72];
  __shared__ __align__(16) u16 ldsX[32 * 72];
  __shared__ int soff[33];
  __shared__ int smid[32];
  __shared__ u8 permAr[32];
  __shared__ u16 eidx[ECAP];
  int w = threadIdx.x >> 6;
  int lane = threadIdx.x & 63;
  int sub = lane >> 3;
  int fo = (lane & 7) * 8;
  int blockBase = blockIdx.x * 32;
  const u16* gsrc;
  int ebase0, scnt;

  GATHER_PROLOGUE(soff, smid, permAr, eidx, blockBase, n_nodes, offsets, midoff, csr_src, gsrc, ebase0, scnt)

  int ln = permAr[w * 8 + sub];
  int node = blockBase + ln;
  bool valid = node < n_nodes;
  int ls = soff[ln] - ebase0;
  int le = soff[ln + 1] - ebase0;
  if (!valid) le = ls;
  int lm = valid ? smid[ln] - ebase0 : ls;
  if (lm < ls) lm = ls;
  if (lm > le) lm = le;
  int lrow = ln * 72;

  uint4 xr = make_uint4(0, 0, 0, 0);
  if (valid) xr = *(const uint4*)(h + ((size_t)node << 6) + fo);
  *(uint4*)&ldsX[lrow + fo] = xr;

  f32x2 a0[4] = {{0,0},{0,0},{0,0},{0,0}};
  f32x2 a1[4] = {{0,0},{0,0},{0,0},{0,0}};
  GATHER_LOOP(h, fo, ls, lm, a0, a1)
  GATHER_LOOP(h, fo, lm, le, a0, a1)
#pragma unroll
  for (int k = 0; k < 4; k++) a0[k] += a1[k];

  uint4 pa;
  pa.x = (u32)f2bf(a0[0].x) | ((u32)f2bf(a0[0].y) << 16);
  pa.y = (u32)f2bf(a0[1].x) | ((u32)f2bf(a0[1].y) << 16);
  pa.z = (u32)f2bf(a0[2].x) | ((u32)f2bf(a0[2].y) << 16);
  pa.w = (u32)f2bf(a0[3].x) | ((u32)f2bf(a0[3].y) << 16);
  *(uint4*)&ldsA[lrow + fo] = pa;
  __syncthreads();

  int mt = w & 1;
  int ntb = (w >> 1) * 2;
  int lr = lane & 15, lk = lane >> 4;
  int arow = (mt * 16 + lr) * 72;
  bf16x8 af0 = *(const bf16x8*)&ldsA[arow + lk * 8];
  bf16x8 af1 = *(const bf16x8*)&ldsA[arow + 32 + lk * 8];
  bf16x8 xf0 = *(const bf16x8*)&ldsX[arow + lk * 8];
  bf16x8 xf1 = *(const bf16x8*)&ldsX[arow + 32 + lk * 8];
#pragma unroll
  for (int tt = 0; tt < 2; tt++) {
    int nt = ntb + tt;
    int wrow = (nt * 16 + lr) * D + lk * 8;
    bf16x8 br0 = *(const bf16x8*)(WbTrel + wrow);
    bf16x8 br1 = *(const bf16x8*)(WbTrel + wrow + 32);
    bf16x8 bo0 = *(const bf16x8*)(WbTroot + wrow);
    bf16x8 bo1 = *(const bf16x8*)(WbTroot + wrow + 32);
    f32x4 acc = {0.0f, 0.0f, 0.0f, 0.0f};
    acc = __builtin_amdgcn_mfma_f32_16x16x32_bf16(af0, br0, acc, 0, 0, 0);
    acc = __builtin_amdgcn_mfma_f32_16x16x32_bf16(af1, br1, acc, 0, 0, 0);
    acc = __builtin_amdgcn_mfma_f32_16x16x32_bf16(xf0, bo0, acc, 0, 0, 0);
    acc = __builtin_amdgcn_mfma_f32_16x16x32_bf16(xf1, bo1, acc, 0, 0, 0);
    float bias = brel[nt * 16 + lr];
#pragma unroll
    for (int r = 0; r < 4; r++) {
      int onode = blockBase + mt * 16 + lk * 4 + r;
      if (onode < n_nodes) {
        float v = acc[r] + bias;
        if (do_relu) v = fmaxf(v, 0.0f);
        h_out[((size_t)onode << 6) + nt * 16 + lr] = f2bf(v);
      }
    }
  }
}

// ===========================================================================
// pool3: SRC-STATIONARY layer-3 pooled aggregation. One block per src-bucket:
// stage 256 h2 rows in LDS (sequential reads!), counting-sort the bucket's
// edges by g=batch[dst] (batch is 200KB -> L2-resident), accumulate per-g in
// registers (subgroup owns 4 graphs), flush to 1 of NREP pooled replicas.
// Replaces 1.25M random 128B line reads with a 6.4MB sequential stream.
// ===========================================================================
__global__ __launch_bounds__(256) void pool3_kernel(
    const u16* __restrict__ h2, const u32* __restrict__ binned2,
    const int* __restrict__ cursors2, const int* __restrict__ batch,
    float* __restrict__ rep, int n_nodes) {
  __shared__ __align__(16) u16 h2lds[256 * 72];
  __shared__ u8 sortedSrc[BCAP];
  __shared__ int ghist[128], gcur[128], gstart[128];
  __shared__ int red2[128];
  int b = blockIdx.x, t = threadIdx.x;
  int cnt = cursors2[b];
  if (cnt < 0) cnt = 0;
  if (cnt > BCAP) cnt = BCAP;
  int srcBase = b << 8;
  int nn = n_nodes - srcBase;
  if (nn > 256) nn = 256;

  // stage h2 tile (coalesced)
  for (int i = t; i < nn * 8; i += 256) {
    int row = i >> 3, ch = i & 7;
    *(uint4*)&h2lds[row * 72 + ch * 8] =
        *(const uint4*)(h2 + ((size_t)(srcBase + row) << 6) + ch * 8);
  }
  if (t < 128) ghist[t] = 0;
  __syncthreads();

  const u32* be = binned2 + (size_t)b * BCAP;
  for (int i = t; i < cnt; i += 256) {
    int g = batch[be[i] & 0xffffu];
    atomicAdd(&ghist[g], 1);
  }
  __syncthreads();
  if (t < 128) red2[t] = ghist[t];
  __syncthreads();
  for (int off = 1; off < 128; off <<= 1) {
    int tmp = (t >= off && t < 128) ? red2[t - off] : 0;
    __syncthreads();
    if (t < 128) red2[t] += tmp;
    __syncthreads();
  }
  if (t < 128) {
    gstart[t] = red2[t] - ghist[t];
    gcur[t] = red2[t] - ghist[t];
  }
  __syncthreads();
  for (int i = t; i < cnt; i += 256) {
    u32 e = be[i];
    int g = batch[e & 0xffffu];
    int p = atomicAdd(&gcur[g], 1);
    sortedSrc[p] = (u8)((e >> 16) & 0xffu);
  }
  __syncthreads();

  // subgroup sg handles graphs {sg, sg+32, sg+64, sg+96}
  int sg = t >> 3, l8 = t & 7;
  float acc[4][8];
#pragma unroll
  for (int k = 0; k < 4; k++)
#pragma unroll
    for (int j = 0; j < 8; j++) acc[k][j] = 0.0f;
#pragma unroll
  for (int k = 0; k < 4; k++) {
    int g = sg + 32 * k;
    int s = gstart[g], e = s + ghist[g];
    for (int i = s; i < e; i++) {
      int sl = sortedSrc[i];
      uint4 r = *(const uint4*)&h2lds[sl * 72 + l8 * 8];
      f32x2 p0 = bfpair(r.x), p1 = bfpair(r.y), p2 = bfpair(r.z), p3 = bfpair(r.w);
      acc[k][0] += p0.x; acc[k][1] += p0.y; acc[k][2] += p1.x; acc[k][3] += p1.y;
      acc[k][4] += p2.x; acc[k][5] += p2.y; acc[k][6] += p3.x; acc[k][7] += p3.y;
    }
  }
  float* myrep = rep + (size_t)(b & (NREP - 1)) * (N_GRAPHS * D);
#pragma unroll
  for (int k = 0; k < 4; k++) {
    int g = sg + 32 * k;
    if (ghist[g] > 0) {
#pragma unroll
      for (int j = 0; j < 8; j++)
        atomicAdd(myrep + g * D + l8 * 8 + j, acc[k][j]);
    }
  }
}

// ===========================================================================
// final: per graph — sum pooledA replicas, pool h2 over own contiguous
// segment (pooledH), then out = meanA@M1 + meanH@M2 + cvec (blin if empty).
// ===========================================================================
__global__ __launch_bounds__(256) void final_kernel(
    const u16* __restrict__ h2, const float* __restrict__ rep,
    const float* __restrict__ M1, const float* __restrict__ M2,
    const float* __restrict__ cvec, const float* __restrict__ blin,
    const int* __restrict__ batch, float* __restrict__ out, int n_nodes) {
  __shared__ int seg[2];
  __shared__ float redH[256];
  __shared__ float mA[64], mH[64];
  int g = blockIdx.x, t = threadIdx.x;
  if (t < 2) {
    int target = g + t;
    int lo = 0, hi = n_nodes;
    while (lo < hi) {
      int mid = (lo + hi) >> 1;
      if (batch[mid] < target) lo = mid + 1; else hi = mid;
    }
    seg[t] = lo;
  }
  __syncthreads();
  int start = seg[0], end = seg[1];
  int f = t & 63, sub = t >> 6;
  float aH = 0.0f;
  for (int n = start + sub; n < end; n += 4)
    aH += bf2f(h2[((size_t)n << 6) + f]);
  redH[t] = aH;
  __syncthreads();
  if (t < 64) {
    float sA = 0.0f;
#pragma unroll
    for (int r = 0; r < NREP; r++)
      sA += rep[(size_t)r * (N_GRAPHS * D) + g * D + t];
    float inv = (end > start) ? 1.0f / (float)(end - start) : 0.0f;
    mA[t] = sA * inv;
    mH[t] = (redH[t] + redH[64 + t] + redH[128 + t] + redH[192 + t]) * inv;
  }
  __syncthreads();
  if (t < D_OUT) {
    float res;
    if (end > start) {
      float acc = cvec[t];
#pragma unroll
      for (int k = 0; k < D; k++)
        acc = fmaf(mA[k], M1[k * D_OUT + t],
              fmaf(mH[k], M2[k * D_OUT + t], acc));
      res = acc;
    } else {
      res = blin[t];
    }
    out[g * D_OUT + t] = res;
  }
}

extern "C" void kernel_launch(void* const* d_in, const int* in_sizes, int n_in,
                              void* d_out, int out_size, void* d_ws, size_t ws_size,
                              hipStream_t stream) {
  const float* x     = (const float*)d_in[0];
  const int*   ei    = (const int*)d_in[1];
  const int*   batch = (const int*)d_in[3];
  const float* Wrel1 = (const float*)d_in[4];
  const float* brel1 = (const float*)d_in[5];
  const float* Wroot1= (const float*)d_in[6];
  const float* Wrel2 = (const float*)d_in[7];
  const float* brel2 = (const float*)d_in[8];
  const float* Wroot2= (const float*)d_in[9];
  const float* Wrel3 = (const float*)d_in[10];
  const float* brel3 = (const float*)d_in[11];
  const float* Wroot3= (const float*)d_in[12];
  const float* Wlin  = (const float*)d_in[13];
  const float* blin  = (const float*)d_in[14];
  float* out = (float*)d_out;

  const int n_edges = in_sizes[1] / 2;
  const int n_nodes = in_sizes[0] / D;
  const int* src = ei;
  const int* dst = ei + n_edges;
  const int nbuck = (n_nodes + 255) >> 8;  // 196
  const int halfThresh = n_nodes / 2;

  // ---- workspace carve-up ----
  char* p = (char*)d_ws;
  u32* binned  = (u32*)p;    p += (size_t)nbuck * BCAP * sizeof(u32);
  u32* binned2 = (u32*)p;    p += (size_t)nbuck * BCAP * sizeof(u32);
  int* cursors = (int*)p;    p += 256 * sizeof(int);                   // memset zone start
  int* cursors2= (int*)p;    p += 256 * sizeof(int);
  float* rep   = (float*)p;  p += (size_t)NREP * N_GRAPHS * D * sizeof(float); // memset zone end
  float* M1     = (float*)p; p += (size_t)D * D_OUT * sizeof(float);
  float* M2     = (float*)p; p += (size_t)D * D_OUT * sizeof(float);
  float* cvec   = (float*)p; p += 16 * sizeof(float);
  int* offsets  = (int*)p;   p += (size_t)(n_nodes + 4) * sizeof(int);
  int* midoff   = (int*)p;   p += (size_t)(n_nodes + 4) * sizeof(int);
  u16* hX       = (u16*)p;   p += (size_t)n_nodes * D * sizeof(u16);
  u16* h1       = (u16*)p;   p += (size_t)n_nodes * D * sizeof(u16);
  u16* h2       = (u16*)p;   p += (size_t)n_nodes * D * sizeof(u16);
  u16* csr_src  = (u16*)p;   p += (size_t)n_edges * sizeof(u16);
  u16* WbT1r    = (u16*)p;   p += (size_t)D * D * sizeof(u16);
  u16* WbT1o    = (u16*)p;   p += (size_t)D * D * sizeof(u16);
  u16* WbT2r    = (u16*)p;   p += (size_t)D * D * sizeof(u16);
  u16* WbT2o    = (u16*)p;   p += (size_t)D * D * sizeof(u16);

  const int bin_blocks = (n_edges + TILE - 1) / TILE;   // 306
  const int cvt_n4 = n_nodes * D / 4;
  const int cvt_blocks = (cvt_n4 + 255) / 256;          // 3125
  const int fused_blocks = (n_nodes + 31) / 32;         // 1563

  const size_t zero_bytes = 512 * sizeof(int)
      + (size_t)NREP * N_GRAPHS * D * sizeof(float);
  hipMemsetAsync(cursors, 0, zero_bytes, stream);

  cvtbin_kernel<<<2 * bin_blocks + cvt_blocks, 256, 0, stream>>>(
      x, hX, cvt_n4, bin_blocks, src, dst, cursors, binned, cursors2, binned2,
      n_edges, nbuck,
      Wrel1, Wroot1, Wrel2, Wroot2, Wrel3, Wroot3, Wlin, brel3, blin,
      M1, M2, cvec, WbT1r, WbT1o, WbT2r, WbT2o);
  csr_kernel<<<nbuck, 256, 0, stream>>>(
      binned, cursors, csr_src, offsets, midoff, n_nodes, nbuck, halfThresh);

  fused_layer_kernel<<<fused_blocks, 256, 0, stream>>>(
      hX, offsets, midoff, csr_src, WbT1r, WbT1o, brel1, h1, n_nodes, 1);
  fused_layer_kernel<<<fused_blocks, 256, 0, stream>>>(
      h1, offsets, midoff, csr_src, WbT2r, WbT2o, brel2, h2, n_nodes, 1);

  // layer-3 pooled aggregation: src-stationary, no random gather
  pool3_kernel<<<nbuck, 256, 0, stream>>>(
      h2, binned2, cursors2, batch, rep, n_nodes);

  final_kernel<<<N_GRAPHS, 256, 0, stream>>>(
      h2, rep, M1, M2, cvec, blin, batch, out, n_nodes);
}

// Round 12
// 218.923 us; speedup vs baseline: 1.4568x; 1.4568x over previous
//
#include <hip/hip_runtime.h>

#define D 64
#define N_GRAPHS 128
#define D_OUT 16
#define BCAP 16384   // max edges per 256-node bucket (avg 6400, sigma ~80)
#define TILE 4096    // edges per bin_kernel block
#define ECAP 2048    // max edges per 32-node block staged in LDS (avg 800)

typedef unsigned short u16;
typedef unsigned int u32;
typedef unsigned char u8;
typedef __attribute__((ext_vector_type(8))) short bf16x8;
typedef __attribute__((ext_vector_type(4))) float f32x4;
typedef __attribute__((ext_vector_type(2))) float f32x2;

__device__ inline u16 f2bf(float f) {  // round-to-nearest-even
  u32 u = __float_as_uint(f);
  return (u16)((u + 0x7fffu + ((u >> 16) & 1u)) >> 16);
}
__device__ inline float bf2f(u16 b) { return __uint_as_float((u32)b << 16); }
__device__ inline f32x2 bfpair(u32 v) {
  return (f32x2){__uint_as_float(v << 16), __uint_as_float(v & 0xffff0000u)};
}

// ===========================================================================
// Merged front-end: blocks [0,nbin) = edge binning; blocks [nbin,...) =
// x->bf16 convert + weight precompute (overlap on CU array). cursors pre-zeroed.
// ===========================================================================
__global__ __launch_bounds__(256) void cvtbin_kernel(
    const float* __restrict__ xin, u16* __restrict__ hX, int n4, int nbin,
    const int* __restrict__ src, const int* __restrict__ dst,
    int* __restrict__ cursors, u32* __restrict__ binned, int n_edges, int nbuck,
    const float* __restrict__ Wrel1, const float* __restrict__ Wroot1,
    const float* __restrict__ Wrel2, const float* __restrict__ Wroot2,
    const float* __restrict__ Wrel3, const float* __restrict__ Wroot3,
    const float* __restrict__ Wlin, const float* __restrict__ brel3,
    const float* __restrict__ blin,
    float* __restrict__ M1, float* __restrict__ M2, float* __restrict__ cvec,
    u16* __restrict__ WbT1r, u16* __restrict__ WbT1o,
    u16* __restrict__ WbT2r, u16* __restrict__ WbT2o) {
  __shared__ u32 ent[TILE];
  __shared__ u8 ebk[TILE];
  __shared__ int hist[256];
  __shared__ int startb[256];
  __shared__ int cur[256];
  __shared__ int gbase[256];
  int t = threadIdx.x;

  if ((int)blockIdx.x < nbin) {
    hist[t] = 0;
    __syncthreads();
    int base = blockIdx.x * TILE;
    int cnt = n_edges - base;
    if (cnt > TILE) cnt = TILE;

    int mys[16], myd[16];
#pragma unroll
    for (int j = 0; j < 16; j++) {
      int i = base + t + j * 256;
      if (t + j * 256 < cnt) {
        mys[j] = src[i];
        myd[j] = dst[i];
        atomicAdd(&hist[myd[j] >> 8], 1);
      } else {
        myd[j] = -1;
      }
    }
    __syncthreads();
    int myc = hist[t];
    for (int off = 1; off < 256; off <<= 1) {
      int tmp = (t >= off) ? hist[t - off] : 0;
      __syncthreads();
      hist[t] += tmp;
      __syncthreads();
    }
    int excl = hist[t] - myc;
    startb[t] = excl;
    cur[t] = excl;
    __syncthreads();

#pragma unroll
    for (int j = 0; j < 16; j++) {
      if (myd[j] >= 0) {
        int b = myd[j] >> 8;
        int p = atomicAdd(&cur[b], 1);
        ent[p] = ((u32)myd[j] << 16) | (u32)mys[j];
        ebk[p] = (u8)b;
      }
    }
    __syncthreads();

    if (t < nbuck && myc > 0) gbase[t] = atomicAdd(&cursors[t], myc);
    __syncthreads();

#pragma unroll
    for (int j = 0; j < 16; j++) {
      int p = t + j * 256;
      if (p < cnt) {
        int b = ebk[p];
        int gpos = gbase[b] + (p - startb[b]);
        if (gpos < BCAP) binned[(size_t)b * BCAP + gpos] = ent[p];
      }
    }
    return;
  }

  int cb = blockIdx.x - nbin;
  if (cb == 0) {
    if (t >= 240) {
      int o = t - 240;
      float c = blin[o];
#pragma unroll
      for (int j = 0; j < D; j++) c = fmaf(brel3[j], Wlin[j * D_OUT + o], c);
      cvec[o] = c;
    }
  } else if (cb <= 8) {
    int idx = (cb - 1) * 256 + t;
    const float* W = (idx < 1024) ? Wrel3 : Wroot3;
    float* M = (idx < 1024) ? M1 : M2;
    int id = idx & 1023;
    int k = id >> 4, o = id & 15;
    float acc = 0.0f;
#pragma unroll
    for (int j = 0; j < D; j++) acc = fmaf(W[k * D + j], Wlin[j * D_OUT + o], acc);
    M[id] = acc;
  } else if (cb <= 16) {
    int tid = (cb - 9) * 256 + t;
    int mat = tid >> 9;
    int r = tid & 511;
    int o = r >> 3;
    int k0 = (r & 7) * 8;
    const float* Wsrc = (mat == 0) ? Wrel1 : (mat == 1) ? Wroot1
                       : (mat == 2) ? Wrel2 : Wroot2;
    u16* Wdst = (mat == 0) ? WbT1r : (mat == 1) ? WbT1o
               : (mat == 2) ? WbT2r : WbT2o;
    u16 tmp[8];
#pragma unroll
    for (int j = 0; j < 8; j++) tmp[j] = f2bf(Wsrc[(k0 + j) * D + o]);
    uint4 pw;
    pw.x = (u32)tmp[0] | ((u32)tmp[1] << 16);
    pw.y = (u32)tmp[2] | ((u32)tmp[3] << 16);
    pw.z = (u32)tmp[4] | ((u32)tmp[5] << 16);
    pw.w = (u32)tmp[6] | ((u32)tmp[7] << 16);
    *(uint4*)&Wdst[o * D + k0] = pw;
  }
  int i = cb * 256 + t;
  if (i >= n4) return;
  float4 v = ((const float4*)xin)[i];
  ushort4 o4;
  o4.x = f2bf(v.x); o4.y = f2bf(v.y); o4.z = f2bf(v.z); o4.w = f2bf(v.w);
  ((ushort4*)hX)[i] = o4;
}

// ===========================================================================
// CSR pass 2: per-node segments PARTITIONED by src half [low | high].
// midoff[n] = split point (kept from r10; cost-free and harmless).
// ===========================================================================
__global__ __launch_bounds__(256) void csr_kernel(
    const u32* __restrict__ binned, const int* __restrict__ cursors,
    u16* __restrict__ csr_src, int* __restrict__ offsets,
    int* __restrict__ midoff, int n_nodes, int nbuck, int halfThresh) {
  __shared__ int deg2[512];   // [node][half]
  __shared__ int cur2[512];
  __shared__ int red[256];
  __shared__ u16 lcsr[BCAP];
  int b = blockIdx.x, t = threadIdx.x;
  int cnt = cursors[b];
  if (cnt < 0) cnt = 0;
  if (cnt > BCAP) cnt = BCAP;

  // ebase = sum of counts of buckets < b
  int c = 0;
  if (t < b) {
    c = cursors[t];
    if (c < 0) c = 0;
    if (c > BCAP) c = BCAP;
  }
  red[t] = c;
  __syncthreads();
  for (int off = 128; off > 0; off >>= 1) {
    if (t < off) red[t] += red[t + off];
    __syncthreads();
  }
  int ebase = red[0];

  int nodeBase = b << 8;
  int nn = n_nodes - nodeBase;
  if (nn > 256) nn = 256;

  deg2[t] = 0;
  deg2[t + 256] = 0;
  __syncthreads();
  const u32* be = binned + (size_t)b * BCAP;
  for (int i = t; i < cnt; i += 256) {
    u32 e = be[i];
    int ln = (e >> 16) - nodeBase;
    int half = ((int)(e & 0xffffu) >= halfThresh) ? 1 : 0;
    atomicAdd(&deg2[ln * 2 + half], 1);
  }
  __syncthreads();
  int lowc = deg2[t * 2], highc = deg2[t * 2 + 1];
  int myTotal = lowc + highc;
  // inclusive scan of per-node totals
  red[t] = myTotal;
  __syncthreads();
  for (int off = 1; off < 256; off <<= 1) {
    int tmp = (t >= off) ? red[t - off] : 0;
    __syncthreads();
    red[t] += tmp;
    __syncthreads();
  }
  int excl = red[t] - myTotal;
  cur2[t * 2] = excl;
  cur2[t * 2 + 1] = excl + lowc;
  if (t < nn) {
    offsets[nodeBase + t] = ebase + excl;
    midoff[nodeBase + t] = ebase + excl + lowc;
  }
  if (b == nbuck - 1 && t == 0) offsets[n_nodes] = ebase + cnt;
  __syncthreads();

  for (int i = t; i < cnt; i += 256) {
    u32 e = be[i];
    int ln = (e >> 16) - nodeBase;
    int half = ((int)(e & 0xffffu) >= halfThresh) ? 1 : 0;
    int p = atomicAdd(&cur2[ln * 2 + half], 1);
    lcsr[p] = (u16)(e & 0xffffu);
  }
  __syncthreads();
  for (int i = t; i < cnt; i += 256) csr_src[ebase + i] = lcsr[i];
}

#define ACC8(a, r) \
  a[0] += bfpair(r.x); a[1] += bfpair(r.y); a[2] += bfpair(r.z); a[3] += bfpair(r.w);

// Prologue: soff/smid -> LDS, degree-rank perm, contiguous csr run -> LDS.
#define GATHER_PROLOGUE(soff, smid, permAr, eidx, blockBase, n_nodes, offsets, midoff, csr_src, gsrc, ebase0, scnt) \
  {                                                                     \
    int t_ = threadIdx.x;                                               \
    if (t_ < 33) {                                                      \
      int idx = blockBase + t_;                                         \
      if (idx > n_nodes) idx = n_nodes;                                 \
      soff[t_] = offsets[idx];                                          \
    }                                                                   \
    if (t_ >= 64 && t_ < 96) {                                          \
      int n_ = t_ - 64;                                                 \
      int idx = blockBase + n_;                                         \
      smid[n_] = (idx < n_nodes) ? midoff[idx] : 0;                     \
    }                                                                   \
    __syncthreads();                                                    \
    ebase0 = soff[0];                                                   \
    int ecnt_ = soff[32] - ebase0;                                      \
    scnt = ecnt_ < ECAP ? ecnt_ : ECAP;                                 \
    gsrc = csr_src + ebase0;                                            \
    if (t_ < 32) {                                                      \
      int d_ = (blockBase + t_ < n_nodes) ? soff[t_ + 1] - soff[t_] : -1; \
      int r_ = 0;                                                       \
      for (int j_ = 0; j_ < 32; j_++) {                                 \
        int dj_ = (blockBase + j_ < n_nodes) ? soff[j_ + 1] - soff[j_] : -1; \
        if (dj_ > d_ || (dj_ == d_ && j_ < t_)) r_++;                   \
      }                                                                 \
      permAr[r_] = (u8)t_;                                              \
    }                                                                   \
    for (int e_ = t_; e_ < scnt; e_ += 256) eidx[e_] = gsrc[e_];        \
    __syncthreads();                                                    \
  }

#define IDX(i) ((i) < ECAP ? (int)eidx[i] : (int)gsrc[i])

// 4-deep unrolled gather body, full 16B row reads.
#define GATHER_LOOP(h, fo, ls, le, a0, a1)                                   \
  {                                                                          \
    int i = ls;                                                              \
    for (; i + 3 < le; i += 4) {                                             \
      int s0 = IDX(i), s1 = IDX(i + 1), s2 = IDX(i + 2), s3 = IDX(i + 3);    \
      uint4 r0 = *(const uint4*)(h + ((size_t)s0 << 6) + fo);                \
      uint4 r1 = *(const uint4*)(h + ((size_t)s1 << 6) + fo);                \
      uint4 r2 = *(const uint4*)(h + ((size_t)s2 << 6) + fo);                \
      uint4 r3 = *(const uint4*)(h + ((size_t)s3 << 6) + fo);                \
      ACC8(a0, r0) ACC8(a1, r1) ACC8(a0, r2) ACC8(a1, r3)                    \
    }                                                                        \
    for (; i < le; i++) {                                                    \
      int s0 = IDX(i);                                                       \
      uint4 r0 = *(const uint4*)(h + ((size_t)s0 << 6) + fo);                \
      ACC8(a0, r0)                                                           \
    }                                                                        \
  }

// ===========================================================================
// Fused layer (layers 1,2): 2 sub-passes over src halves -> LDS bf16 ->
// 4 waves x 8 mfma_f32_16x16x32_bf16 -> bias/relu -> h_out.
// ===========================================================================
__global__ __launch_bounds__(256) void fused_layer_kernel(
    const u16* __restrict__ h, const int* __restrict__ offsets,
    const int* __restrict__ midoff, const u16* __restrict__ csr_src,
    const u16* __restrict__ WbTrel, const u16* __restrict__ WbTroot,
    const float* __restrict__ brel,
    u16* __restrict__ h_out, int n_nodes, int do_relu) {
  __shared__ __align__(16) u16 ldsA[32 * 72];
  __shared__ __align__(16) u16 ldsX[32 * 72];
  __shared__ int soff[33];
  __shared__ int smid[32];
  __shared__ u8 permAr[32];
  __shared__ u16 eidx[ECAP];
  int w = threadIdx.x >> 6;
  int lane = threadIdx.x & 63;
  int sub = lane >> 3;
  int fo = (lane & 7) * 8;
  int blockBase = blockIdx.x * 32;
  const u16* gsrc;
  int ebase0, scnt;

  GATHER_PROLOGUE(soff, smid, permAr, eidx, blockBase, n_nodes, offsets, midoff, csr_src, gsrc, ebase0, scnt)

  int ln = permAr[w * 8 + sub];
  int node = blockBase + ln;
  bool valid = node < n_nodes;
  int ls = soff[ln] - ebase0;
  int le = soff[ln + 1] - ebase0;
  if (!valid) le = ls;
  int lm = valid ? smid[ln] - ebase0 : ls;
  if (lm < ls) lm = ls;
  if (lm > le) lm = le;
  int lrow = ln * 72;

  uint4 xr = make_uint4(0, 0, 0, 0);
  if (valid) xr = *(const uint4*)(h + ((size_t)node << 6) + fo);
  *(uint4*)&ldsX[lrow + fo] = xr;

  f32x2 a0[4] = {{0,0},{0,0},{0,0},{0,0}};
  f32x2 a1[4] = {{0,0},{0,0},{0,0},{0,0}};
  GATHER_LOOP(h, fo, ls, lm, a0, a1)
  GATHER_LOOP(h, fo, lm, le, a0, a1)
#pragma unroll
  for (int k = 0; k < 4; k++) a0[k] += a1[k];

  uint4 pa;
  pa.x = (u32)f2bf(a0[0].x) | ((u32)f2bf(a0[0].y) << 16);
  pa.y = (u32)f2bf(a0[1].x) | ((u32)f2bf(a0[1].y) << 16);
  pa.z = (u32)f2bf(a0[2].x) | ((u32)f2bf(a0[2].y) << 16);
  pa.w = (u32)f2bf(a0[3].x) | ((u32)f2bf(a0[3].y) << 16);
  *(uint4*)&ldsA[lrow + fo] = pa;
  __syncthreads();

  // ---- MFMA dense phase: OUT[32x64] = A@Wrel + X@Wroot + b ----
  int mt = w & 1;
  int ntb = (w >> 1) * 2;
  int lr = lane & 15, lk = lane >> 4;
  int arow = (mt * 16 + lr) * 72;
  bf16x8 af0 = *(const bf16x8*)&ldsA[arow + lk * 8];
  bf16x8 af1 = *(const bf16x8*)&ldsA[arow + 32 + lk * 8];
  bf16x8 xf0 = *(const bf16x8*)&ldsX[arow + lk * 8];
  bf16x8 xf1 = *(const bf16x8*)&ldsX[arow + 32 + lk * 8];
#pragma unroll
  for (int tt = 0; tt < 2; tt++) {
    int nt = ntb + tt;
    int wrow = (nt * 16 + lr) * D + lk * 8;
    bf16x8 br0 = *(const bf16x8*)(WbTrel + wrow);
    bf16x8 br1 = *(const bf16x8*)(WbTrel + wrow + 32);
    bf16x8 bo0 = *(const bf16x8*)(WbTroot + wrow);
    bf16x8 bo1 = *(const bf16x8*)(WbTroot + wrow + 32);
    f32x4 acc = {0.0f, 0.0f, 0.0f, 0.0f};
    acc = __builtin_amdgcn_mfma_f32_16x16x32_bf16(af0, br0, acc, 0, 0, 0);
    acc = __builtin_amdgcn_mfma_f32_16x16x32_bf16(af1, br1, acc, 0, 0, 0);
    acc = __builtin_amdgcn_mfma_f32_16x16x32_bf16(xf0, bo0, acc, 0, 0, 0);
    acc = __builtin_amdgcn_mfma_f32_16x16x32_bf16(xf1, bo1, acc, 0, 0, 0);
    float bias = brel[nt * 16 + lr];
#pragma unroll
    for (int r = 0; r < 4; r++) {
      int onode = blockBase + mt * 16 + lk * 4 + r;
      if (onode < n_nodes) {
        float v = acc[r] + bias;
        if (do_relu) v = fmaxf(v, 0.0f);
        h_out[((size_t)onode << 6) + nt * 16 + lr] = f2bf(v);
      }
    }
  }
}

// ===========================================================================
// Layer 3 gather + pool: 2 sub-pass gather; block-level run-length
// reduction over sorted graph ids -> ~1 atomic per (graph,feature) run.
// ===========================================================================
__global__ __launch_bounds__(256) void gather_pool_kernel(
    const u16* __restrict__ h, const int* __restrict__ offsets,
    const int* __restrict__ midoff, const u16* __restrict__ csr_src,
    const int* __restrict__ batch,
    float* __restrict__ pooledA, float* __restrict__ pooledH, int n_nodes) {
  __shared__ int soff[33];
  __shared__ int smid[32];
  __shared__ u8 permAr[32];
  __shared__ u16 eidx[ECAP];
  __shared__ int gid[32];
  __shared__ float ldsPA[32][D];
  __shared__ float ldsPH[32][D];
  int w = threadIdx.x >> 6;
  int lane = threadIdx.x & 63;
  int sub = lane >> 3;
  int fo = (lane & 7) * 8;
  int blockBase = blockIdx.x * 32;
  if (threadIdx.x < 32)
    gid[threadIdx.x] = (blockBase + threadIdx.x < n_nodes) ? batch[blockBase + threadIdx.x] : -1;
  const u16* gsrc;
  int ebase0, scnt;

  GATHER_PROLOGUE(soff, smid, permAr, eidx, blockBase, n_nodes, offsets, midoff, csr_src, gsrc, ebase0, scnt)

  int ln = permAr[w * 8 + sub];
  int node = blockBase + ln;
  bool valid = node < n_nodes;
  int ls = soff[ln] - ebase0;
  int le = soff[ln + 1] - ebase0;
  if (!valid) le = ls;
  int lm = valid ? smid[ln] - ebase0 : ls;
  if (lm < ls) lm = ls;
  if (lm > le) lm = le;

  f32x2 a0[4] = {{0,0},{0,0},{0,0},{0,0}};
  f32x2 a1[4] = {{0,0},{0,0},{0,0},{0,0}};
  GATHER_LOOP(h, fo, ls, lm, a0, a1)
  GATHER_LOOP(h, fo, lm, le, a0, a1)
#pragma unroll
  for (int k = 0; k < 4; k++) a0[k] += a1[k];

  uint4 xr = make_uint4(0, 0, 0, 0);
  if (valid) xr = *(const uint4*)(h + ((size_t)node << 6) + fo);
  f32x2 x0 = bfpair(xr.x), x1 = bfpair(xr.y), x2 = bfpair(xr.z), x3 = bfpair(xr.w);
  float* rowA = &ldsPA[ln][fo];
  float* rowH = &ldsPH[ln][fo];
  rowA[0] = a0[0].x; rowA[1] = a0[0].y; rowA[2] = a0[1].x; rowA[3] = a0[1].y;
  rowA[4] = a0[2].x; rowA[5] = a0[2].y; rowA[6] = a0[3].x; rowA[7] = a0[3].y;
  rowH[0] = x0.x; rowH[1] = x0.y; rowH[2] = x1.x; rowH[3] = x1.y;
  rowH[4] = x2.x; rowH[5] = x2.y; rowH[6] = x3.x; rowH[7] = x3.y;
  __syncthreads();

  if (threadIdx.x < 128) {
    int half = threadIdx.x >> 6;
    int f = threadIdx.x & 63;
    float* dst = half ? pooledH : pooledA;
    float acc = 0.0f;
    int curg = -1;
#pragma unroll 1
    for (int n = 0; n < 32; n++) {
      int g = gid[n];
      if (g < 0) break;
      float v = half ? ldsPH[n][f] : ldsPA[n][f];
      if (g != curg) {
        if (curg >= 0) atomicAdd(dst + curg * D + f, acc);
        curg = g;
        acc = v;
      } else {
        acc += v;
      }
    }
    if (curg >= 0) atomicAdd(dst + curg * D + f, acc);
  }
}

// out[g,o] = meanA@M1 + meanH@M2 + cvec  (blin if graph empty).
__global__ __launch_bounds__(64) void final_kernel(
    const float* __restrict__ pooledA, const float* __restrict__ pooledH,
    const float* __restrict__ M1, const float* __restrict__ M2,
    const float* __restrict__ cvec, const float* __restrict__ blin,
    const int* __restrict__ batch, float* __restrict__ out, int n_nodes) {
  __shared__ int seg[2];
  int g = blockIdx.x;
  int t = threadIdx.x;
  if (t < 2) {
    int target = g + t;
    int lo = 0, hi = n_nodes;
    while (lo < hi) {
      int mid = (lo + hi) >> 1;
      if (batch[mid] < target) lo = mid + 1; else hi = mid;
    }
    seg[t] = lo;
  }
  __syncthreads();
  int cnt = seg[1] - seg[0];
  if (t < D_OUT) {
    float res;
    if (cnt > 0) {
      float inv = 1.0f / (float)cnt;
      float acc = cvec[t];
#pragma unroll
      for (int k = 0; k < D; k++)
        acc = fmaf(pooledA[g * D + k] * inv, M1[k * D_OUT + t],
              fmaf(pooledH[g * D + k] * inv, M2[k * D_OUT + t], acc));
      res = acc;
    } else {
      res = blin[t];
    }
    out[g * D_OUT + t] = res;
  }
}

extern "C" void kernel_launch(void* const* d_in, const int* in_sizes, int n_in,
                              void* d_out, int out_size, void* d_ws, size_t ws_size,
                              hipStream_t stream) {
  const float* x     = (const float*)d_in[0];
  const int*   ei    = (const int*)d_in[1];
  const int*   batch = (const int*)d_in[3];
  const float* Wrel1 = (const float*)d_in[4];
  const float* brel1 = (const float*)d_in[5];
  const float* Wroot1= (const float*)d_in[6];
  const float* Wrel2 = (const float*)d_in[7];
  const float* brel2 = (const float*)d_in[8];
  const float* Wroot2= (const float*)d_in[9];
  const float* Wrel3 = (const float*)d_in[10];
  const float* brel3 = (const float*)d_in[11];
  const float* Wroot3= (const float*)d_in[12];
  const float* Wlin  = (const float*)d_in[13];
  const float* blin  = (const float*)d_in[14];
  float* out = (float*)d_out;

  const int n_edges = in_sizes[1] / 2;
  const int n_nodes = in_sizes[0] / D;
  const int* src = ei;
  const int* dst = ei + n_edges;
  const int nbuck = (n_nodes + 255) >> 8;  // 196
  const int halfThresh = n_nodes / 2;

  // ---- workspace carve-up ----
  char* p = (char*)d_ws;
  u32* binned  = (u32*)p;    p += (size_t)nbuck * BCAP * sizeof(u32);
  int* cursors = (int*)p;    p += 256 * sizeof(int);                   // memset zone start
  float* pooledA = (float*)p; p += (size_t)N_GRAPHS * D * sizeof(float);
  float* pooledH = (float*)p; p += (size_t)N_GRAPHS * D * sizeof(float); // memset zone end
  float* M1     = (float*)p; p += (size_t)D * D_OUT * sizeof(float);
  float* M2     = (float*)p; p += (size_t)D * D_OUT * sizeof(float);
  float* cvec   = (float*)p; p += 16 * sizeof(float);
  int* offsets  = (int*)p;   p += (size_t)(n_nodes + 4) * sizeof(int);
  int* midoff   = (int*)p;   p += (size_t)(n_nodes + 4) * sizeof(int);
  u16* hX       = (u16*)p;   p += (size_t)n_nodes * D * sizeof(u16);
  u16* h1       = (u16*)p;   p += (size_t)n_nodes * D * sizeof(u16);
  u16* h2       = (u16*)p;   p += (size_t)n_nodes * D * sizeof(u16);
  u16* csr_src  = (u16*)p;   p += (size_t)n_edges * sizeof(u16);
  u16* WbT1r    = (u16*)p;   p += (size_t)D * D * sizeof(u16);
  u16* WbT1o    = (u16*)p;   p += (size_t)D * D * sizeof(u16);
  u16* WbT2r    = (u16*)p;   p += (size_t)D * D * sizeof(u16);
  u16* WbT2o    = (u16*)p;   p += (size_t)D * D * sizeof(u16);

  const int bin_blocks = (n_edges + TILE - 1) / TILE;   // 306
  const int cvt_n4 = n_nodes * D / 4;
  const int cvt_blocks = (cvt_n4 + 255) / 256;          // 3125
  const int fused_blocks = (n_nodes + 31) / 32;         // 1563

  const size_t zero_bytes = 256 * sizeof(int) + 2 * (size_t)N_GRAPHS * D * sizeof(float);
  hipMemsetAsync(cursors, 0, zero_bytes, stream);

  cvtbin_kernel<<<bin_blocks + cvt_blocks, 256, 0, stream>>>(
      x, hX, cvt_n4, bin_blocks, src, dst, cursors, binned, n_edges, nbuck,
      Wrel1, Wroot1, Wrel2, Wroot2, Wrel3, Wroot3, Wlin, brel3, blin,
      M1, M2, cvec, WbT1r, WbT1o, WbT2r, WbT2o);
  csr_kernel<<<nbuck, 256, 0, stream>>>(
      binned, cursors, csr_src, offsets, midoff, n_nodes, nbuck, halfThresh);

  fused_layer_kernel<<<fused_blocks, 256, 0, stream>>>(
      hX, offsets, midoff, csr_src, WbT1r, WbT1o, brel1, h1, n_nodes, 1);
  fused_layer_kernel<<<fused_blocks, 256, 0, stream>>>(
      h1, offsets, midoff, csr_src, WbT2r, WbT2o, brel2, h2, n_nodes, 1);

  gather_pool_kernel<<<fused_blocks, 256, 0, stream>>>(
      h2, offsets, midoff, csr_src, batch, pooledA, pooledH, n_nodes);

  final_kernel<<<N_GRAPHS, 64, 0, stream>>>(
      pooledA, pooledH, M1, M2, cvec, blin, batch, out, n_nodes);
}